// Round 13
// baseline (135.212 us; speedup 1.0000x reference)
//
#include <hip/hip_runtime.h>

// Single-scale fixed-size deformable attention.
// value: (BS,H*W,NH,HD) f32; sloc: (BS,NQ,NH,1,NP,2); aw: (BS,NQ,NH,1,NP)
// out:   (BS,NQ,NH*HD) f32
//
// Ladder: R5 51.5us (XCD slab swizzle, FETCH=compulsory). R9 47.5us (asm
// 16-deep MLP) -> L2 gather service pinned ~108G lines/s (13.8 TB/s @128B).
// R10 (fp16 + x-pairing, 64B-aligned): ~42us total -- 1.5 lines/pair (50%
// straddle). R11: explicit pair duplication -> vh[bh][y][x] = 128B entry
// {pixel x, pixel x+1} x 32ch fp16. Every pair-load = exactly 1 aligned line:
// 2.56M lines (0.5x R9). Slab = HW*128B = 1.28MB (same residency as R5).

constexpr int BS = 4, NQ = 10000, NH = 8, HD = 32, NP = 4, H = 100, W = 100;
constexpr int HW = H * W;
constexpr unsigned VH_BYTES = (unsigned)BS * NH * HW * 128u;   // 40,960,000

typedef float    f32x4 __attribute__((ext_vector_type(4)));
typedef float    f32x8 __attribute__((ext_vector_type(8)));
typedef _Float16 f16x8 __attribute__((ext_vector_type(8)));
typedef unsigned u32x4 __attribute__((ext_vector_type(4)));

// ---- Pass 1: (b,pix,h,c) f32 -> vh[bh][y][x] = {pix(y,x), pix(y,x+1)} fp16 ----
__global__ __launch_bounds__(256)
void cast_dup_kernel(const float* __restrict__ v, _Float16* __restrict__ vh)
{
    const int tid  = blockIdx.x * 256 + (int)threadIdx.x;   // 640,000 threads
    const int half = tid & 1;                               // which pixel of the pair
    const int t2   = tid >> 1;                              // entry index [0, 320K)
    const int x    = t2 % W;
    const int t3   = t2 / W;
    const int y    = t3 % H;
    const int bh   = t3 / H;                                // b*NH + h
    const int px   = min(x + half, W - 1);                  // clamp-dup right edge

    // src: 32 f32 channels of pixel (y,px), head h. Plain (cached) loads:
    // each source line is read by two entries (x and x-1).
    const float* src = v + ((size_t)(bh >> 3) * HW + (size_t)(y * W + px)) * (NH * HD)
                         + (bh & 7) * HD;
    f16x8 o[4];
#pragma unroll
    for (int i = 0; i < 4; ++i) {
        const f32x4 a = *(const f32x4*)(src + i * 8);
        const f32x4 c = *(const f32x4*)(src + i * 8 + 4);
        const f32x8 f = {a.x, a.y, a.z, a.w, c.x, c.y, c.z, c.w};
        o[i] = __builtin_convertvector(f, f16x8);
    }
    // dst: 64B half-entry; consecutive threads -> contiguous 128B entries.
    _Float16* dst = vh + (size_t)t2 * 64 + half * 32;
#pragma unroll
    for (int i = 0; i < 4; ++i)
        *(f16x8*)(dst + i * 8) = o[i];
}

// ---- Pass 2: 1-line-per-pair gather ----
__global__ __launch_bounds__(256, 4)
void gather_kernel(const _Float16* __restrict__ vh,
                   const float* __restrict__ sloc,
                   const float* __restrict__ aw,
                   float* __restrict__ out)
{
    // XCD slab swizzle (R5-verified): XCD x streams slabs [4x,4x+4)
    // sequentially; concurrent working set 1.28MB < 4MB XCD L2.
    const int chunk = gridDim.x >> 3;                    // 1250
    const int swz   = (blockIdx.x & 7) * chunk + (blockIdx.x >> 3);

    const int tid   = swz * 256 + (int)threadIdx.x;
    const int group = tid >> 3;                          // bh*NQ + q
    const int lane  = tid & 7;
    const int xsel  = lane >> 2;                         // 0: x0 corner, 1: x1
    const int csel  = lane & 3;                          // 8-ch chunk (16B fp16)

    const int q  = group % NQ;                           // magic-mul
    const int bh = group / NQ;
    const int h  = bh & (NH - 1);
    const int b  = bh >> 3;
    const int bq = b * NQ + q;

    // Per-group params (broadcast 16B loads).
    const size_t pbase = (size_t)bq * NH + h;
    const f32x4 l01 = *(const f32x4*)(sloc + pbase * (NP * 2));
    const f32x4 l23 = *(const f32x4*)(sloc + pbase * (NP * 2) + 4);
    const f32x4 wv  = *(const f32x4*)(aw   + pbase * NP);

    const float lx[NP] = {l01.x, l01.z, l23.x, l23.z};
    const float ly[NP] = {l01.y, l01.w, l23.y, l23.w};
    const float wp[NP] = {wv.x,  wv.y,  wv.z,  wv.w};

    const unsigned slabbase = (unsigned)(bh * HW) * 128u;  // 128B per entry

    unsigned voff[NP][2];
    float    wrow[NP][2];       // fy weight per row (0 if row invalid)
    float    wxl[NP];           // this lane's x-weight * aw (0 if x invalid)
#pragma unroll
    for (int p = 0; p < NP; ++p) {
        const float x = lx[p] * (float)W - 0.5f;    // align_corners=False unnorm
        const float y = ly[p] * (float)H - 0.5f;
        const float x0f = floorf(x);
        const float y0f = floorf(y);
        const int   x0  = (int)x0f, y0 = (int)y0f;
        const float fx1 = x - x0f, fx0 = 1.f - fx1;
        const float fy1 = y - y0f, fy0 = 1.f - fy1;

        const int xc = x0 + xsel;                   // lane's x corner
        wxl[p] = ((unsigned)xc < (unsigned)W) ? (xsel ? fx1 : fx0) * wp[p] : 0.f;
        wrow[p][0] = ((unsigned)y0 < (unsigned)H)       ? fy0 : 0.f;
        wrow[p][1] = ((unsigned)(y0 + 1) < (unsigned)H) ? fy1 : 0.f;

        const int basex = min(max(x0, 0), W - 1);   // entry = pixels (basex, basex+1)
        const int sl    = min(max(xc, 0), W - 1) - basex;   // slot 0/1 (0 if w=0)
        const int y0c   = min(max(y0, 0), H - 1);
        const int y1c   = min(max(y0 + 1, 0), H - 1);
        const unsigned lo = (unsigned)sl * 64u + (unsigned)csel * 16u;
        voff[p][0] = slabbase + (unsigned)(y0c * W + basex) * 128u + lo;
        voff[p][1] = slabbase + (unsigned)(y1c * W + basex) * 128u + lo;
    }

    // SRSRC over the paired fp16 copy.
    union { const _Float16* p; unsigned u[2]; } va; va.p = vh;
    const u32x4 rsrc = {va.u[0], va.u[1] & 0xFFFFu, VH_BYTES, 0x00020000u};

    // Issue all 8 pair-loads back-to-back (volatile: cannot be re-serialized).
    // Each is 8 lanes x 16B = 128B, 128B-aligned -> exactly 1 L2 line.
    f32x4 r00, r01, r10, r11, r20, r21, r30, r31;
#define GLOAD(dst, off) \
    asm volatile("buffer_load_dwordx4 %0, %1, %2, 0 offen" \
                 : "=v"(dst) : "v"(off), "s"(rsrc))
    GLOAD(r00, voff[0][0]); GLOAD(r01, voff[0][1]);
    GLOAD(r10, voff[1][0]); GLOAD(r11, voff[1][1]);
    GLOAD(r20, voff[2][0]); GLOAD(r21, voff[2][1]);
    GLOAD(r30, voff[3][0]); GLOAD(r31, voff[3][1]);
#undef GLOAD

    f32x8 acc = (f32x8)(0.f);
#define CONSUME(ra, rb, p, cnt) \
    asm volatile("s_waitcnt vmcnt(" #cnt ")" : "+v"(ra), "+v"(rb)); \
    { const f32x8 v0 = __builtin_convertvector(__builtin_bit_cast(f16x8, ra), f32x8); \
      const f32x8 v1 = __builtin_convertvector(__builtin_bit_cast(f16x8, rb), f32x8); \
      acc += v0 * (wxl[p] * wrow[p][0]) + v1 * (wxl[p] * wrow[p][1]); }
    CONSUME(r00, r01, 0, 6)
    CONSUME(r10, r11, 1, 4)
    CONSUME(r20, r21, 2, 2)
    CONSUME(r30, r31, 3, 0)
#undef CONSUME

    // Combine x0-partials (lanes 0-3) with x1-partials (lanes 4-7).
    f32x8 other;
#pragma unroll
    for (int j = 0; j < 8; ++j) other[j] = __shfl_xor(acc[j], 4, 8);
    acc += other;

    // Lane writes its 16B quarter: channels csel*8 + xsel*4 .. +4.
    const f32x4 res = xsel ? (f32x4){acc[4], acc[5], acc[6], acc[7]}
                           : (f32x4){acc[0], acc[1], acc[2], acc[3]};
    __builtin_nontemporal_store(res,
        (f32x4*)(out + (size_t)bq * (NH * HD) + h * HD + csel * 8 + xsel * 4));
}

// ---- Fallback (R9-style f32 direct gather) if ws is too small ----
__global__ __launch_bounds__(256, 4)
void deform_attn_f32(const float* __restrict__ value,
                     const float* __restrict__ sloc,
                     const float* __restrict__ aw,
                     float* __restrict__ out)
{
    const int chunk = gridDim.x >> 3;
    const int swz   = (blockIdx.x & 7) * chunk + (blockIdx.x >> 3);
    const int tid   = swz * 256 + (int)threadIdx.x;
    const int group = tid >> 3;
    const int lane  = tid & 7;
    const int q  = group % NQ;
    const int bh = group / NQ;
    const int h  = bh & (NH - 1);
    const int b  = bh >> 3;
    const int bq = b * NQ + q;
    const size_t pbase = (size_t)bq * NH + h;
    const f32x4 l01 = *(const f32x4*)(sloc + pbase * (NP * 2));
    const f32x4 l23 = *(const f32x4*)(sloc + pbase * (NP * 2) + 4);
    const f32x4 wv  = *(const f32x4*)(aw   + pbase * NP);
    const float lx[NP] = {l01.x, l01.z, l23.x, l23.z};
    const float ly[NP] = {l01.y, l01.w, l23.y, l23.w};
    const float wp[NP] = {wv.x,  wv.y,  wv.z,  wv.w};
    const float* vbase = value + (size_t)b * HW * NH * HD + h * HD + lane * 4;
    f32x4 acc = (f32x4)(0.f);
#pragma unroll
    for (int p = 0; p < NP; ++p) {
        const float x = lx[p] * (float)W - 0.5f;
        const float y = ly[p] * (float)H - 0.5f;
        const float x0f = floorf(x), y0f = floorf(y);
        const int x0 = (int)x0f, y0 = (int)y0f, x1 = x0 + 1, y1 = y0 + 1;
        const float wx1 = x - x0f, wx0 = 1.f - wx1, wy1 = y - y0f, wy0 = 1.f - wy1;
        const bool vx0 = (unsigned)x0 < (unsigned)W, vx1 = (unsigned)x1 < (unsigned)W;
        const bool vy0 = (unsigned)y0 < (unsigned)H, vy1 = (unsigned)y1 < (unsigned)H;
        const int xc0 = min(max(x0, 0), W - 1), xc1 = min(max(x1, 0), W - 1);
        const int yc0 = min(max(y0, 0), H - 1), yc1 = min(max(y1, 0), H - 1);
        const float w00 = (vx0 && vy0) ? wp[p] * wx0 * wy0 : 0.f;
        const float w10 = (vx1 && vy0) ? wp[p] * wx1 * wy0 : 0.f;
        const float w01 = (vx0 && vy1) ? wp[p] * wx0 * wy1 : 0.f;
        const float w11 = (vx1 && vy1) ? wp[p] * wx1 * wy1 : 0.f;
        const f32x4 v00 = *(const f32x4*)(vbase + (size_t)(yc0 * W + xc0) * (NH * HD));
        const f32x4 v10 = *(const f32x4*)(vbase + (size_t)(yc0 * W + xc1) * (NH * HD));
        const f32x4 v01 = *(const f32x4*)(vbase + (size_t)(yc1 * W + xc0) * (NH * HD));
        const f32x4 v11 = *(const f32x4*)(vbase + (size_t)(yc1 * W + xc1) * (NH * HD));
        acc += w00 * v00 + w10 * v10 + w01 * v01 + w11 * v11;
    }
    __builtin_nontemporal_store(acc, (f32x4*)(out + (size_t)bq * (NH * HD) + h * HD + lane * 4));
}

extern "C" void kernel_launch(void* const* d_in, const int* in_sizes, int n_in,
                              void* d_out, int out_size, void* d_ws, size_t ws_size,
                              hipStream_t stream) {
    const float* value = (const float*)d_in[0];
    // d_in[1] = value_spatial_shapes (int64) — unused in fixed-size variant
    const float* sloc  = (const float*)d_in[2];
    const float* aw    = (const float*)d_in[3];
    float*       out   = (float*)d_out;

    if (ws_size >= (size_t)VH_BYTES) {
        _Float16* vh = (_Float16*)d_ws;
        cast_dup_kernel<<<2500, 256, 0, stream>>>(value, vh);   // 640K threads
        gather_kernel<<<10000, 256, 0, stream>>>(vh, sloc, aw, out);
    } else {
        deform_attn_f32<<<10000, 256, 0, stream>>>(value, sloc, aw, out);
    }
}